// Round 12
// baseline (226.545 us; speedup 1.0000x reference)
//
#include <hip/hip_runtime.h>
#include <hip/hip_bf16.h>
#include <math.h>

// Problem constants
#define B_    2
#define NH_   8
#define NL_   4
#define NP_   4
#define HD_   32
#define S_    13294
#define L_    13294
#define M_    26588

__device__ __constant__ int c_H[NL_]     = {100, 50, 25, 13};
__device__ __constant__ int c_W[NL_]     = {100, 50, 25, 13};
__device__ __constant__ int c_start[NL_] = {0, 10000, 12500, 13125};

typedef __attribute__((ext_vector_type(8))) _Float16 f16x8;
typedef __attribute__((ext_vector_type(2))) _Float16 f16x2;
typedef __attribute__((ext_vector_type(4))) float    float4v;

__device__ __forceinline__ unsigned short f2h(float f) {
    _Float16 h = (_Float16)f;
    return __builtin_bit_cast(unsigned short, h);
}
__device__ __forceinline__ float h2f(unsigned short u) {
    _Float16 h = __builtin_bit_cast(_Float16, u);
    return (float)h;
}
__device__ __forceinline__ f16x2 pkrtz(float a, float b) {
    return __builtin_bit_cast(f16x2, __builtin_amdgcn_cvt_pkrtz(a, b));
}

// ---------------------------------------------------------------------------
// Weight prep: transpose W's to [N][K] fp16, fused off|attn weights + bias.
// ---------------------------------------------------------------------------
__global__ __launch_bounds__(256) void prep_weights(
    const float* __restrict__ W_val, const float* __restrict__ W_off,
    const float* __restrict__ W_attn, const float* __restrict__ b_off,
    const float* __restrict__ b_attn, const float* __restrict__ W_out,
    unsigned short* __restrict__ wt_val, unsigned short* __restrict__ wt_oa,
    unsigned short* __restrict__ wt_out, float* __restrict__ bias_oa)
{
    int i = blockIdx.x * 256 + threadIdx.x;
    if (i < 65536) {
        int n = i >> 8, k = i & 255;
        wt_val[i] = f2h(W_val[k * 256 + n]);
    } else if (i < 65536 + 98304) {
        int j = i - 65536;
        int n = j >> 8, k = j & 255;   // n in [0,384)
        float v = (n < 256) ? W_off[k * 256 + n] : W_attn[k * 128 + (n - 256)];
        wt_oa[j] = f2h(v);
    } else if (i < 65536 + 98304 + 65536) {
        int j = i - 163840;
        int n = j >> 8, k = j & 255;
        wt_out[j] = f2h(W_out[k * 256 + n]);
    } else if (i < 229376 + 384) {
        int j = i - 229376;
        bias_oa[j] = (j < 256) ? b_off[j] : b_attn[j - 256];
    }
}

// ---------------------------------------------------------------------------
// WAVE-AUTONOMOUS MFMA GEMM body: ZERO __syncthreads.
//   Each wave owns 32 rows x 64 cols. A is staged by the wave itself into
//   its PRIVATE LDS region (same-wave ds_write -> ds_read is in-order; no
//   barrier needed -- the deform-v6-proven mechanism). B fragments direct
//   from global [N][K] fp16, register-prefetched one full K-iter ahead.
//   Block = 4 waves = 128 rows x 64 cols; grid.y = column slice.
//   Identical per-output K-order / pkrtz pairing as before -> bit-identical.
//   OUT: 0 = fp16 stride 256, 1 = fp16 stride 384, 2 = fp32 stride 256.
// ---------------------------------------------------------------------------
template<int NT, int OUT, bool AF32>
__device__ __forceinline__ void gemm_wv(
    const void* __restrict__ Av,
    const unsigned short* __restrict__ WT,
    const float* __restrict__ bias,
    void* __restrict__ Cv,
    unsigned short (* __restrict__ sA)[2][32][40],   // [wave][buf][row][40]
    int colBase)
{
    const int tid  = threadIdx.x;
    const int lane = tid & 63;
    const int wave = tid >> 6;
    const int rowBase = blockIdx.x * 128 + wave * 32;   // wave's 32 rows

    const int ar  = lane >> 2;          // stage row within 16-row pass
    const int ako = (lane & 3) * 8;     // stage k offset within BK=32
    const int fr  = lane & 15;
    const int fk  = (lane >> 4) * 8;

    float4v acc[2][NT] = {};

    const unsigned short* bbase[NT];
#pragma unroll
    for (int t = 0; t < NT; ++t)
        bbase[t] = WT + (size_t)(colBase + t * 16 + fr) * 256 + fk;

    f16x8 curB[NT], nxtB[NT];
    float4 ra0, ra1, rb0, rb1;          // fp32 staging regs (pass a, pass b)
    f16x8  rah_a, rah_b;                // fp16 staging regs

    auto loadA = [&](int k0) {
        const int r0 = rowBase + ar;
        const int r1 = rowBase + 16 + ar;
        if constexpr (AF32) {
            const float* A = (const float*)Av;
            if (r0 < M_) {
                ra0 = *reinterpret_cast<const float4*>(A + (size_t)r0 * 256 + k0 + ako);
                ra1 = *reinterpret_cast<const float4*>(A + (size_t)r0 * 256 + k0 + ako + 4);
            } else { ra0 = make_float4(0.f,0.f,0.f,0.f); ra1 = ra0; }
            if (r1 < M_) {
                rb0 = *reinterpret_cast<const float4*>(A + (size_t)r1 * 256 + k0 + ako);
                rb1 = *reinterpret_cast<const float4*>(A + (size_t)r1 * 256 + k0 + ako + 4);
            } else { rb0 = make_float4(0.f,0.f,0.f,0.f); rb1 = rb0; }
        } else {
            const unsigned short* A = (const unsigned short*)Av;
            rah_a = (r0 < M_) ? *reinterpret_cast<const f16x8*>(A + (size_t)r0 * 256 + k0 + ako)
                              : f16x8{};
            rah_b = (r1 < M_) ? *reinterpret_cast<const f16x8*>(A + (size_t)r1 * 256 + k0 + ako)
                              : f16x8{};
        }
    };
    auto packA = [&](const float4& u0, const float4& u1) -> f16x8 {
        const f16x2 p0 = pkrtz(u0.x, u0.y);
        const f16x2 p1 = pkrtz(u0.z, u0.w);
        const f16x2 p2 = pkrtz(u1.x, u1.y);
        const f16x2 p3 = pkrtz(u1.z, u1.w);
        f16x8 s;
        s[0]=p0[0]; s[1]=p0[1]; s[2]=p1[0]; s[3]=p1[1];
        s[4]=p2[0]; s[5]=p2[1]; s[6]=p3[0]; s[7]=p3[1];
        return s;
    };
    auto storeA = [&](int buf) {
        f16x8 sa, sb;
        if constexpr (AF32) { sa = packA(ra0, ra1); sb = packA(rb0, rb1); }
        else                { sa = rah_a;           sb = rah_b;           }
        *reinterpret_cast<f16x8*>(&sA[wave][buf][ar][ako])      = sa;
        *reinterpret_cast<f16x8*>(&sA[wave][buf][16 + ar][ako]) = sb;
    };
    auto loadB = [&](f16x8* dst, int k0) {
#pragma unroll
        for (int t = 0; t < NT; ++t)
            dst[t] = *reinterpret_cast<const f16x8*>(bbase[t] + k0);
    };

    // prologue
    loadA(0);
    loadB(curB, 0);
    storeA(0);
    loadA(32);

#pragma unroll
    for (int it = 0; it < 8; ++it) {
        // same-wave LDS write (prev iter) -> read here: in-order, no barrier
        f16x8 af0 = *reinterpret_cast<const f16x8*>(&sA[wave][it & 1][fr][fk]);
        f16x8 af1 = *reinterpret_cast<const f16x8*>(&sA[wave][it & 1][16 + fr][fk]);
        if (it < 7) {
            storeA((it + 1) & 1);              // regs loaded at it-1 -> full-iter slack
            if (it < 6) loadA((it + 2) * 32);
            loadB(nxtB, (it + 1) * 32);        // in flight across the MFMAs below
        }
#pragma unroll
        for (int nt = 0; nt < NT; ++nt)
            acc[0][nt] = __builtin_amdgcn_mfma_f32_16x16x32_f16(
                af0, curB[nt], acc[0][nt], 0, 0, 0);
#pragma unroll
        for (int nt = 0; nt < NT; ++nt)
            acc[1][nt] = __builtin_amdgcn_mfma_f32_16x16x32_f16(
                af1, curB[nt], acc[1][nt], 0, 0, 0);
        if (it < 7) {
#pragma unroll
            for (int t = 0; t < NT; ++t) curB[t] = nxtB[t];
        }
    }

    const int dn  = lane & 15;
    const int dm0 = (lane >> 4) * 4;
#pragma unroll
    for (int mt = 0; mt < 2; ++mt) {
#pragma unroll
        for (int nt = 0; nt < NT; ++nt) {
            const int col = colBase + nt * 16 + dn;
            const float bv = bias[col];
#pragma unroll
            for (int r = 0; r < 4; ++r) {
                const int row = rowBase + mt * 16 + dm0 + r;
                if (row < M_) {
                    const float v = acc[mt][nt][r] + bv;
                    if constexpr (OUT == 0)
                        ((unsigned short*)Cv)[(size_t)row * 256 + col] = f2h(v);
                    else if constexpr (OUT == 1)
                        ((unsigned short*)Cv)[(size_t)row * 384 + col] = f2h(v);
                    else
                        ((float*)Cv)[(size_t)row * 256 + col] = v;
                }
            }
        }
    }
}

// value proj (y=0..3: cols y*64) + off/attn proj (y=4..9: cols (y-4)*64).
// 208 x-blocks x 10 y-slices = 2080 blocks, all waves barrier-free.
__global__ __launch_bounds__(256) void gemm_vq(
    const float* __restrict__ value, const float* __restrict__ query,
    const unsigned short* __restrict__ wt_val, const unsigned short* __restrict__ wt_oa,
    const float* __restrict__ b_val, const float* __restrict__ bias_oa,
    unsigned short* __restrict__ val_f16, unsigned short* __restrict__ oa_f16)
{
    __shared__ unsigned short sA[4][2][32][40];   // 20 KB, per-wave regions
    const int y = blockIdx.y;
    if (y < 4)
        gemm_wv<4, 0, true>(value, wt_val, b_val, val_f16, sA, y * 64);
    else
        gemm_wv<4, 1, true>(query, wt_oa, bias_oa, oa_f16, sA, (y - 4) * 64);
}

// output projection: out = acc_f16 @ wt_out^T + b_out (fp32 out)
__global__ __launch_bounds__(256) void gemm_out3(
    const unsigned short* __restrict__ Af16,
    const unsigned short* __restrict__ WT,
    const float* __restrict__ bias, float* __restrict__ C)
{
    __shared__ unsigned short sA[4][2][32][40];
    gemm_wv<4, 2, false>(Af16, WT, bias, C, sA, blockIdx.y * 64);
}

// ---------------------------------------------------------------------------
// Deformable sampling v6 (measured floor, 52.8us). Unchanged.
// ---------------------------------------------------------------------------
__global__ __launch_bounds__(256, 8) void deform_sample_v6(
    const unsigned short* __restrict__ val,  // [B,S,256] fp16
    const float* __restrict__ refp,          // [B,L,4,2]
    const unsigned short* __restrict__ oa,   // [M,384] fp16
    unsigned short* __restrict__ acc)        // [M,256] fp16
{
    __shared__ int sP[4][1088];              // 17.4 KB, per-wave region

    const int tid  = threadIdx.x;
    const int wave = tid >> 6;
    const int l    = tid & 63;

    const int q   = l >> 5;                  // 0..1 (query within wave)
    const int h   = (l >> 2) & 7;            // head
    const int lvl = l & 3;                   // phase-1: level; phase-2: d4
    const int qw  = blockIdx.x * 8 + wave * 2 + q;
    const int bq  = min(qw, M_ - 1);

    int* __restrict__ sw = sP[wave];

    // ---- phase 1: softmax weights + corner packs (wave-local) ----
    {
        const int2 lgi = *reinterpret_cast<const int2*>(
            oa + (size_t)bq * 384 + 256 + h * 16 + lvl * 4);
        const f16x2 lp0 = __builtin_bit_cast(f16x2, lgi.x);
        const f16x2 lp1 = __builtin_bit_cast(f16x2, lgi.y);
        float lg[4] = { (float)lp0[0], (float)lp0[1], (float)lp1[0], (float)lp1[1] };

        float m = fmaxf(fmaxf(lg[0], lg[1]), fmaxf(lg[2], lg[3]));
        m = fmaxf(m, __shfl_xor(m, 1));
        m = fmaxf(m, __shfl_xor(m, 2));

        float e[4], s = 0.f;
#pragma unroll
        for (int j = 0; j < 4; ++j) { e[j] = __expf(lg[j] - m); s += e[j]; }
        s += __shfl_xor(s, 1);
        s += __shfl_xor(s, 2);
        const float rinv = 1.f / s;

        const int Wi = c_W[lvl], Hi = c_H[lvl], st = c_start[lvl];
        const float2 rxy = *reinterpret_cast<const float2*>(
            refp + ((size_t)bq * NL_ + lvl) * 2);
        const f16x8 off8 = *reinterpret_cast<const f16x8*>(
            oa + (size_t)bq * 384 + h * 32 + lvl * 8);

#pragma unroll
        for (int j = 0; j < 4; ++j) {        // j == point p
            const float wgt = e[j] * rinv;
            const float x = rxy.x * (float)Wi + (float)off8[2 * j]     - 0.5f;
            const float y = rxy.y * (float)Hi + (float)off8[2 * j + 1] - 0.5f;
            const float x0f = floorf(x), y0f = floorf(y);
            const int   x0 = (int)x0f,   y0 = (int)y0f;
            const float wx1 = x - x0f, wx0 = 1.f - wx1;
            const float wy1 = y - y0f, wy0 = 1.f - wy1;

            const int   cx[4] = {x0, x0 + 1, x0,     x0 + 1};
            const int   cy[4] = {y0, y0,     y0 + 1, y0 + 1};
            const float cw[4] = {wx0 * wy0, wx1 * wy0, wx0 * wy1, wx1 * wy1};
            const int base = q * 544 + (lvl * 4 + j) * 34 + h;
#pragma unroll
            for (int c = 0; c < 4; ++c) {
                const bool inb = (cx[c] >= 0) & (cx[c] < Wi) & (cy[c] >= 0) & (cy[c] < Hi);
                const int xi = min(max(cx[c], 0), Wi - 1);
                const int yi = min(max(cy[c], 0), Hi - 1);
                const int idx = st + yi * Wi + xi;          // < 13294: fits 16 bits
                const unsigned short wh = f2h(inb ? wgt * cw[c] : 0.f);
                sw[base + c * 8] = idx | ((int)wh << 16);
            }
        }
    }
    // same wave wrote, same wave reads: in-order -> no barrier needed.

    // ---- phase 2: gather + weighted accumulate (fp16 pairs) ----
    const int d4 = lvl;
    const unsigned short* vb = val + (size_t)(bq / L_) * S_ * 256 + h * 32 + d4 * 8;
    const int rbase = q * 544 + h;

    f16x2 A0{}, A1{}, A2{}, A3{};
#pragma unroll 8
    for (int i = 0; i < 64; ++i) {
        const int lp = i >> 2;
        const int c  = i & 3;
        const int pk = sw[rbase + lp * 34 + c * 8];
        const unsigned wb = (unsigned)pk >> 16;
        const f16x2 w2 = __builtin_bit_cast(f16x2, (wb << 16) | wb);
        const int4 u = *reinterpret_cast<const int4*>(
            vb + (size_t)((unsigned)pk & 0xffffu) * 256);
        A0 += w2 * __builtin_bit_cast(f16x2, u.x);
        A1 += w2 * __builtin_bit_cast(f16x2, u.y);
        A2 += w2 * __builtin_bit_cast(f16x2, u.z);
        A3 += w2 * __builtin_bit_cast(f16x2, u.w);
    }
    if (qw < M_) {
        int4 o;
        o.x = __builtin_bit_cast(int, A0);
        o.y = __builtin_bit_cast(int, A1);
        o.z = __builtin_bit_cast(int, A2);
        o.w = __builtin_bit_cast(int, A3);
        *reinterpret_cast<int4*>(acc + (size_t)qw * 256 + h * 32 + d4 * 8) = o;
    }
}

// ---------------------------------------------------------------------------
extern "C" void kernel_launch(void* const* d_in, const int* in_sizes, int n_in,
                              void* d_out, int out_size, void* d_ws, size_t ws_size,
                              hipStream_t stream) {
    const float* query  = (const float*)d_in[0];
    const float* refp   = (const float*)d_in[1];
    const float* value  = (const float*)d_in[2];
    const float* W_val  = (const float*)d_in[3];
    const float* b_val  = (const float*)d_in[4];
    const float* W_off  = (const float*)d_in[5];
    const float* b_off  = (const float*)d_in[6];
    const float* W_attn = (const float*)d_in[7];
    const float* b_attn = (const float*)d_in[8];
    const float* W_out  = (const float*)d_in[9];
    const float* b_out  = (const float*)d_in[10];
    float* out = (float*)d_out;

    char* ws = (char*)d_ws;
    const size_t mb = (size_t)M_ * 256;
    unsigned short* val_f16 = (unsigned short*)ws;  ws += mb * 2;
    unsigned short* acc_f16 = (unsigned short*)ws;  ws += mb * 2;
    unsigned short* oa_f16  = (unsigned short*)ws;  ws += (size_t)M_ * 384 * 2;
    unsigned short* wt_val  = (unsigned short*)ws;  ws += 65536 * 2;
    unsigned short* wt_oa   = (unsigned short*)ws;  ws += 98304 * 2;
    unsigned short* wt_out  = (unsigned short*)ws;  ws += 65536 * 2;
    float*          bias_oa = (float*)ws;           ws += 384 * 4;

    dim3 blk(256);
    const int rb = (M_ + 127) / 128;   // 208 row-blocks of 128

    prep_weights<<<dim3(898), blk, 0, stream>>>(
        W_val, W_off, W_attn, b_off, b_attn, W_out, wt_val, wt_oa, wt_out, bias_oa);

    // value proj + off/attn proj (one dispatch, 2080 blocks, barrier-free)
    gemm_vq<<<dim3(rb, 10), blk, 0, stream>>>(
        value, query, wt_val, wt_oa, b_val, bias_oa, val_f16, oa_f16);

    // softmax + sampling (fp16 end-to-end, wave-autonomous)
    deform_sample_v6<<<dim3((M_ + 7) / 8), blk, 0, stream>>>(val_f16, refp, oa_f16, acc_f16);

    // output projection (barrier-free, 832 blocks)
    gemm_out3<<<dim3(rb, 4), blk, 0, stream>>>(acc_f16, wt_out, b_out, out);
}

// Round 13
// 206.425 us; speedup vs baseline: 1.0975x; 1.0975x over previous
//
#include <hip/hip_runtime.h>
#include <hip/hip_bf16.h>
#include <math.h>

// Problem constants
#define B_    2
#define NH_   8
#define NL_   4
#define NP_   4
#define HD_   32
#define S_    13294
#define L_    13294
#define M_    26588

__device__ __constant__ int c_H[NL_]     = {100, 50, 25, 13};
__device__ __constant__ int c_W[NL_]     = {100, 50, 25, 13};
__device__ __constant__ int c_start[NL_] = {0, 10000, 12500, 13125};

typedef __attribute__((ext_vector_type(8))) _Float16 f16x8;
typedef __attribute__((ext_vector_type(2))) _Float16 f16x2;
typedef __attribute__((ext_vector_type(4))) float    float4v;

__device__ __forceinline__ unsigned short f2h(float f) {
    _Float16 h = (_Float16)f;
    return __builtin_bit_cast(unsigned short, h);
}
__device__ __forceinline__ float h2f(unsigned short u) {
    _Float16 h = __builtin_bit_cast(_Float16, u);
    return (float)h;
}
__device__ __forceinline__ f16x2 pkrtz(float a, float b) {
    return __builtin_bit_cast(f16x2, __builtin_amdgcn_cvt_pkrtz(a, b));
}

// ---------------------------------------------------------------------------
// Weight prep: transpose W's to [N][K] fp16, fused off|attn weights + bias.
// ---------------------------------------------------------------------------
__global__ __launch_bounds__(256) void prep_weights(
    const float* __restrict__ W_val, const float* __restrict__ W_off,
    const float* __restrict__ W_attn, const float* __restrict__ b_off,
    const float* __restrict__ b_attn, const float* __restrict__ W_out,
    unsigned short* __restrict__ wt_val, unsigned short* __restrict__ wt_oa,
    unsigned short* __restrict__ wt_out, float* __restrict__ bias_oa)
{
    int i = blockIdx.x * 256 + threadIdx.x;
    if (i < 65536) {
        int n = i >> 8, k = i & 255;
        wt_val[i] = f2h(W_val[k * 256 + n]);
    } else if (i < 65536 + 98304) {
        int j = i - 65536;
        int n = j >> 8, k = j & 255;   // n in [0,384)
        float v = (n < 256) ? W_off[k * 256 + n] : W_attn[k * 128 + (n - 256)];
        wt_oa[j] = f2h(v);
    } else if (i < 65536 + 98304 + 65536) {
        int j = i - 163840;
        int n = j >> 8, k = j & 255;
        wt_out[j] = f2h(W_out[k * 256 + n]);
    } else if (i < 229376 + 384) {
        int j = i - 229376;
        bias_oa[j] = (j < 256) ? b_off[j] : b_attn[j - 256];
    }
}

// ---------------------------------------------------------------------------
// MFMA GEMM body (R4 structure: LDS-staged A, dbuf, 1 barrier/K-iter;
// B direct-from-global, register-prefetched one full iteration ahead).
//   NT = B fragments per wave; wave cols = colBase + wave*NT*16.
//   OUT: 0 = fp16 stride 256, 1 = fp16 stride 384, 2 = fp32 stride 256.
// ---------------------------------------------------------------------------
template<int NT, int OUT, bool AF32>
__device__ __forceinline__ void gemm_body(
    const void* __restrict__ Av,
    const unsigned short* __restrict__ WT,
    const float* __restrict__ bias,
    void* __restrict__ Cv,
    unsigned short (* __restrict__ As)[64][40],
    int colBase)
{
    const int tid  = threadIdx.x;
    const int lane = tid & 63;
    const int wave = tid >> 6;
    const int rowBase = blockIdx.x * 64;
    const int wcol = colBase + wave * (NT * 16);

    const int ar   = tid >> 2;          // A row within tile
    const int ako  = (tid & 3) * 8;     // k offset within BK=32
    const int grow = rowBase + ar;
    const int fr   = lane & 15;
    const int fk   = (lane >> 4) * 8;

    float4v acc[4][NT] = {};

    const unsigned short* bbase[NT];
#pragma unroll
    for (int t = 0; t < NT; ++t)
        bbase[t] = WT + (size_t)(wcol + t * 16 + fr) * 256 + fk;

    f16x8 curB[NT], nxtB[NT];
    float4 ra0, ra1;
    f16x8  rah;

    auto loadA = [&](int k0) {
        if constexpr (AF32) {
            const float* A = (const float*)Av;
            if (grow < M_) {
                ra0 = *reinterpret_cast<const float4*>(A + (size_t)grow * 256 + k0 + ako);
                ra1 = *reinterpret_cast<const float4*>(A + (size_t)grow * 256 + k0 + ako + 4);
            } else { ra0 = make_float4(0.f,0.f,0.f,0.f); ra1 = ra0; }
        } else {
            const unsigned short* A = (const unsigned short*)Av;
            if (grow < M_)
                rah = *reinterpret_cast<const f16x8*>(A + (size_t)grow * 256 + k0 + ako);
            else
                rah = f16x8{};
        }
    };
    auto storeA = [&](int buf) {
        f16x8 s;
        if constexpr (AF32) {
            f16x2 p0 = pkrtz(ra0.x, ra0.y);
            f16x2 p1 = pkrtz(ra0.z, ra0.w);
            f16x2 p2 = pkrtz(ra1.x, ra1.y);
            f16x2 p3 = pkrtz(ra1.z, ra1.w);
            s[0]=p0[0]; s[1]=p0[1]; s[2]=p1[0]; s[3]=p1[1];
            s[4]=p2[0]; s[5]=p2[1]; s[6]=p3[0]; s[7]=p3[1];
        } else {
            s = rah;
        }
        *reinterpret_cast<f16x8*>(&As[buf][ar][ako]) = s;
    };
    auto loadB = [&](f16x8* dst, int k0) {
#pragma unroll
        for (int t = 0; t < NT; ++t)
            dst[t] = *reinterpret_cast<const f16x8*>(bbase[t] + k0);
    };

    // prologue
    loadA(0);
    loadB(curB, 0);
    storeA(0);
    loadA(32);

#pragma unroll
    for (int it = 0; it < 8; ++it) {
        __syncthreads();                       // As[it&1] ready for all waves
        f16x8 af[4];
#pragma unroll
        for (int t = 0; t < 4; ++t)
            af[t] = *reinterpret_cast<const f16x8*>(&As[it & 1][t * 16 + fr][fk]);
        if (it < 7) {
            storeA((it + 1) & 1);              // regs loaded at it-1 -> full-iter slack
            if (it < 6) loadA((it + 2) * 32);
            loadB(nxtB, (it + 1) * 32);        // in flight across the MFMAs below
        }
#pragma unroll
        for (int mt = 0; mt < 4; ++mt)
#pragma unroll
            for (int nt = 0; nt < NT; ++nt)
                acc[mt][nt] = __builtin_amdgcn_mfma_f32_16x16x32_f16(
                    af[mt], curB[nt], acc[mt][nt], 0, 0, 0);
        if (it < 7) {
#pragma unroll
            for (int t = 0; t < NT; ++t) curB[t] = nxtB[t];
        }
    }

    const int dn  = lane & 15;
    const int dm0 = (lane >> 4) * 4;
#pragma unroll
    for (int mt = 0; mt < 4; ++mt) {
#pragma unroll
        for (int nt = 0; nt < NT; ++nt) {
            const int col = wcol + nt * 16 + dn;
            const float bv = bias[col];
#pragma unroll
            for (int r = 0; r < 4; ++r) {
                const int row = rowBase + mt * 16 + dm0 + r;
                if (row < M_) {
                    const float v = acc[mt][nt][r] + bv;
                    if constexpr (OUT == 0)
                        ((unsigned short*)Cv)[(size_t)row * 256 + col] = f2h(v);
                    else if constexpr (OUT == 1)
                        ((unsigned short*)Cv)[(size_t)row * 384 + col] = f2h(v);
                    else
                        ((float*)Cv)[(size_t)row * 256 + col] = v;
                }
            }
        }
    }
}

// value proj (y=0, NT=4) + off/attn proj split into two N=192 slices
// (y=1: cols 0-191, y=2: cols 192-383; NT=3). 1248 blocks (~4.9/CU).
__global__ __launch_bounds__(256) void gemm_vq(
    const float* __restrict__ value, const float* __restrict__ query,
    const unsigned short* __restrict__ wt_val, const unsigned short* __restrict__ wt_oa,
    const float* __restrict__ b_val, const float* __restrict__ bias_oa,
    unsigned short* __restrict__ val_f16, unsigned short* __restrict__ oa_f16)
{
    __shared__ unsigned short As[2][64][40];
    if (blockIdx.y == 0)
        gemm_body<4, 0, true>(value, wt_val, b_val, val_f16, As, 0);
    else if (blockIdx.y == 1)
        gemm_body<3, 1, true>(query, wt_oa, bias_oa, oa_f16, As, 0);
    else
        gemm_body<3, 1, true>(query, wt_oa, bias_oa, oa_f16, As, 192);
}

// output projection: out = acc_f16 @ wt_out^T + b_out (fp32 out)
__global__ __launch_bounds__(256) void gemm_out3(
    const unsigned short* __restrict__ Af16,
    const unsigned short* __restrict__ WT,
    const float* __restrict__ bias, float* __restrict__ C)
{
    __shared__ unsigned short As[2][64][40];
    gemm_body<4, 2, false>(Af16, WT, bias, C, As, 0);
}

// ---------------------------------------------------------------------------
// Deformable sampling v6 (measured floor, 52.8us across 5 structural
// variants: L2 random-gather throughput limit). Unchanged.
// ---------------------------------------------------------------------------
__global__ __launch_bounds__(256, 8) void deform_sample_v6(
    const unsigned short* __restrict__ val,  // [B,S,256] fp16
    const float* __restrict__ refp,          // [B,L,4,2]
    const unsigned short* __restrict__ oa,   // [M,384] fp16
    unsigned short* __restrict__ acc)        // [M,256] fp16
{
    __shared__ int sP[4][1088];              // 17.4 KB, per-wave region

    const int tid  = threadIdx.x;
    const int wave = tid >> 6;
    const int l    = tid & 63;

    const int q   = l >> 5;                  // 0..1 (query within wave)
    const int h   = (l >> 2) & 7;            // head
    const int lvl = l & 3;                   // phase-1: level; phase-2: d4
    const int qw  = blockIdx.x * 8 + wave * 2 + q;
    const int bq  = min(qw, M_ - 1);

    int* __restrict__ sw = sP[wave];

    // ---- phase 1: softmax weights + corner packs (wave-local) ----
    {
        const int2 lgi = *reinterpret_cast<const int2*>(
            oa + (size_t)bq * 384 + 256 + h * 16 + lvl * 4);
        const f16x2 lp0 = __builtin_bit_cast(f16x2, lgi.x);
        const f16x2 lp1 = __builtin_bit_cast(f16x2, lgi.y);
        float lg[4] = { (float)lp0[0], (float)lp0[1], (float)lp1[0], (float)lp1[1] };

        float m = fmaxf(fmaxf(lg[0], lg[1]), fmaxf(lg[2], lg[3]));
        m = fmaxf(m, __shfl_xor(m, 1));
        m = fmaxf(m, __shfl_xor(m, 2));

        float e[4], s = 0.f;
#pragma unroll
        for (int j = 0; j < 4; ++j) { e[j] = __expf(lg[j] - m); s += e[j]; }
        s += __shfl_xor(s, 1);
        s += __shfl_xor(s, 2);
        const float rinv = 1.f / s;

        const int Wi = c_W[lvl], Hi = c_H[lvl], st = c_start[lvl];
        const float2 rxy = *reinterpret_cast<const float2*>(
            refp + ((size_t)bq * NL_ + lvl) * 2);
        const f16x8 off8 = *reinterpret_cast<const f16x8*>(
            oa + (size_t)bq * 384 + h * 32 + lvl * 8);

#pragma unroll
        for (int j = 0; j < 4; ++j) {        // j == point p
            const float wgt = e[j] * rinv;
            const float x = rxy.x * (float)Wi + (float)off8[2 * j]     - 0.5f;
            const float y = rxy.y * (float)Hi + (float)off8[2 * j + 1] - 0.5f;
            const float x0f = floorf(x), y0f = floorf(y);
            const int   x0 = (int)x0f,   y0 = (int)y0f;
            const float wx1 = x - x0f, wx0 = 1.f - wx1;
            const float wy1 = y - y0f, wy0 = 1.f - wy1;

            const int   cx[4] = {x0, x0 + 1, x0,     x0 + 1};
            const int   cy[4] = {y0, y0,     y0 + 1, y0 + 1};
            const float cw[4] = {wx0 * wy0, wx1 * wy0, wx0 * wy1, wx1 * wy1};
            const int base = q * 544 + (lvl * 4 + j) * 34 + h;
#pragma unroll
            for (int c = 0; c < 4; ++c) {
                const bool inb = (cx[c] >= 0) & (cx[c] < Wi) & (cy[c] >= 0) & (cy[c] < Hi);
                const int xi = min(max(cx[c], 0), Wi - 1);
                const int yi = min(max(cy[c], 0), Hi - 1);
                const int idx = st + yi * Wi + xi;          // < 13294: fits 16 bits
                const unsigned short wh = f2h(inb ? wgt * cw[c] : 0.f);
                sw[base + c * 8] = idx | ((int)wh << 16);
            }
        }
    }
    // same wave wrote, same wave reads: in-order -> no barrier needed.

    // ---- phase 2: gather + weighted accumulate (fp16 pairs) ----
    const int d4 = lvl;
    const unsigned short* vb = val + (size_t)(bq / L_) * S_ * 256 + h * 32 + d4 * 8;
    const int rbase = q * 544 + h;

    f16x2 A0{}, A1{}, A2{}, A3{};
#pragma unroll 8
    for (int i = 0; i < 64; ++i) {
        const int lp = i >> 2;
        const int c  = i & 3;
        const int pk = sw[rbase + lp * 34 + c * 8];
        const unsigned wb = (unsigned)pk >> 16;
        const f16x2 w2 = __builtin_bit_cast(f16x2, (wb << 16) | wb);
        const int4 u = *reinterpret_cast<const int4*>(
            vb + (size_t)((unsigned)pk & 0xffffu) * 256);
        A0 += w2 * __builtin_bit_cast(f16x2, u.x);
        A1 += w2 * __builtin_bit_cast(f16x2, u.y);
        A2 += w2 * __builtin_bit_cast(f16x2, u.z);
        A3 += w2 * __builtin_bit_cast(f16x2, u.w);
    }
    if (qw < M_) {
        int4 o;
        o.x = __builtin_bit_cast(int, A0);
        o.y = __builtin_bit_cast(int, A1);
        o.z = __builtin_bit_cast(int, A2);
        o.w = __builtin_bit_cast(int, A3);
        *reinterpret_cast<int4*>(acc + (size_t)qw * 256 + h * 32 + d4 * 8) = o;
    }
}

// ---------------------------------------------------------------------------
extern "C" void kernel_launch(void* const* d_in, const int* in_sizes, int n_in,
                              void* d_out, int out_size, void* d_ws, size_t ws_size,
                              hipStream_t stream) {
    const float* query  = (const float*)d_in[0];
    const float* refp   = (const float*)d_in[1];
    const float* value  = (const float*)d_in[2];
    const float* W_val  = (const float*)d_in[3];
    const float* b_val  = (const float*)d_in[4];
    const float* W_off  = (const float*)d_in[5];
    const float* b_off  = (const float*)d_in[6];
    const float* W_attn = (const float*)d_in[7];
    const float* b_attn = (const float*)d_in[8];
    const float* W_out  = (const float*)d_in[9];
    const float* b_out  = (const float*)d_in[10];
    float* out = (float*)d_out;

    char* ws = (char*)d_ws;
    const size_t mb = (size_t)M_ * 256;
    unsigned short* val_f16 = (unsigned short*)ws;  ws += mb * 2;
    unsigned short* acc_f16 = (unsigned short*)ws;  ws += mb * 2;
    unsigned short* oa_f16  = (unsigned short*)ws;  ws += (size_t)M_ * 384 * 2;
    unsigned short* wt_val  = (unsigned short*)ws;  ws += 65536 * 2;
    unsigned short* wt_oa   = (unsigned short*)ws;  ws += 98304 * 2;
    unsigned short* wt_out  = (unsigned short*)ws;  ws += 65536 * 2;
    float*          bias_oa = (float*)ws;           ws += 384 * 4;

    dim3 blk(256);

    prep_weights<<<dim3(898), blk, 0, stream>>>(
        W_val, W_off, W_attn, b_off, b_attn, W_out, wt_val, wt_oa, wt_out, bias_oa);

    // value proj + off/attn proj (one dispatch, 1248 blocks, 3 N-slices)
    gemm_vq<<<dim3((M_ + 63) / 64, 3), blk, 0, stream>>>(
        value, query, wt_val, wt_oa, b_val, bias_oa, val_f16, oa_f16);

    // softmax + sampling (fp16 end-to-end, wave-autonomous)
    deform_sample_v6<<<dim3((M_ + 7) / 8), blk, 0, stream>>>(val_f16, refp, oa_f16, acc_f16);

    // output projection (R4 LDS form)
    gemm_out3<<<dim3((M_ + 63) / 64), blk, 0, stream>>>(acc_f16, wt_out, b_out, out);
}